// Round 8
// baseline (339.178 us; speedup 1.0000x reference)
//
#include <hip/hip_runtime.h>
#include <hip/hip_bf16.h>

#define D 128
#define CH 2048   // edges per block in CSR partition passes
#define BM 16     // dst rows per fused block (8 waves, balanced edge slicing)

typedef unsigned int u32;
typedef unsigned short u16;
typedef __attribute__((ext_vector_type(8))) short s16x8;
typedef __attribute__((ext_vector_type(4))) float f32x4;
typedef __attribute__((ext_vector_type(2))) float f32x2;
typedef __attribute__((ext_vector_type(2))) u32 u32x2;

__device__ __forceinline__ float bf2f(u16 u) {
    union { u32 u; float f; } v; v.u = ((u32)u) << 16; return v.f;
}
__device__ __forceinline__ u16 f2bf(float f) {
    union { float f; u32 u; } v; v.f = f;
    return (u16)((v.u + 0x7fffu + ((v.u >> 16) & 1u)) >> 16);
}
__device__ __forceinline__ u32 pack_bf2(float a, float b) {
    __hip_bfloat162 t = __float22bfloat162_rn(make_float2(a, b));
    union { __hip_bfloat162 t; u32 u; } v; v.t = t; return v.u;
}

// ---- dtype detector (also zeroes gcnt for the CSR build) ----
__global__ void detect_dtype(const u16* __restrict__ x, int* __restrict__ flag,
                             int* __restrict__ gcnt, int nbuck) {
    __shared__ int cnt;
    if (threadIdx.x == 0) cnt = 0;
    __syncthreads();
    if ((int)threadIdx.x < nbuck) gcnt[threadIdx.x] = 0;
    u16 u = x[2 * threadIdx.x];
    int e = (u >> 7) & 0xFF;
    if (e >= 96 && e <= 150) atomicAdd(&cnt, 1);
    __syncthreads();
    if (threadIdx.x == 0) *flag = (cnt >= 128) ? 0 : 1;
}

// ---- prep1: blocks [0,nconv) expand x bf16->f32 (ONLY when input is bf16);
//             blocks [nconv, nconv+nblkE) run csr_count ----
__global__ __launch_bounds__(256)
void prep1(const u32x2* __restrict__ xin_b, float4* __restrict__ xout,
           long long n4, const int* __restrict__ flag,
           const int* __restrict__ dst, int* __restrict__ gcnt,
           int E, int nbuck, int nconv)
{
    if ((int)blockIdx.x < nconv) {
        if (*flag != 0) return;            // f32 input is used directly
        long long i = (long long)blockIdx.x * 256 + threadIdx.x;
        if (i >= n4) return;
        u32x2 v = xin_b[i];                // 4 bf16
        float4 o;
        o.x = bf2f((u16)(v[0] & 0xffffu));
        o.y = bf2f((u16)(v[0] >> 16));
        o.z = bf2f((u16)(v[1] & 0xffffu));
        o.w = bf2f((u16)(v[1] >> 16));
        xout[i] = o;
    } else {
        __shared__ int scnt[256];
        int tid = threadIdx.x;
        scnt[tid] = 0;
        __syncthreads();
        int base = (blockIdx.x - nconv) * CH;
#pragma unroll
        for (int it = 0; it < CH / 256; ++it) {
            int e = base + it * 256 + tid;
            if (e < E) atomicAdd(&scnt[dst[e] >> 8], 1);
        }
        __syncthreads();
        if (tid < nbuck && scnt[tid] > 0) atomicAdd(&gcnt[tid], scnt[tid]);
    }
}

__global__ __launch_bounds__(256)
void csr_scan(const int* __restrict__ gcnt, int* __restrict__ bstart, int* __restrict__ bcur,
              int nbuck, int N_, int E_, int* __restrict__ offs) {
    __shared__ int wpart[4];
    int tid = threadIdx.x, lane = tid & 63, wid = tid >> 6;
    int v = (tid < nbuck) ? gcnt[tid] : 0;
    int s = v;
#pragma unroll
    for (int off = 1; off < 64; off <<= 1) {
        int t = __shfl_up(s, off, 64);
        if (lane >= off) s += t;
    }
    if (lane == 63) wpart[wid] = s;
    __syncthreads();
    int add = 0;
    for (int w = 0; w < wid; ++w) add += wpart[w];
    int excl = add + s - v;
    if (tid <= nbuck) bstart[tid] = excl;
    if (tid < nbuck)  bcur[tid]  = excl;
    if (tid == 0) offs[N_] = E_;
}

// ---- prep2: blocks [0,nblkE) partition edges into bucket-contiguous ebuf
//             (rec = (dst&255)<<24 | (et<<16) | src);
//             blocks [nblkE, nblkE+18) build fragment-ordered weights wt ----
// wt[layer][plane 0..8][wv:8][ks:4][lane:64][j:8] bf16 ;
// element = W[k = ks*32 + (lane>>4)*8 + j][col = wv*16 + (lane&15)] ; plane 8 = loopW
__global__ __launch_bounds__(256)
void prep2(const int* __restrict__ src, const int* __restrict__ dst,
           const int* __restrict__ et, int* __restrict__ bcur,
           u32* __restrict__ ebuf, int E, int N, int nbuck, int nblkE,
           const void* __restrict__ W1r, const void* __restrict__ lW1r,
           const void* __restrict__ W2r, const void* __restrict__ lW2r,
           const int* __restrict__ flag, int R_, u16* __restrict__ wt)
{
    if ((int)blockIdx.x < nblkE) {
        __shared__ int scnt[256], sbase[256];
        int tid = threadIdx.x;
        scnt[tid] = 0;
        __syncthreads();
        int base = blockIdx.x * CH;
#pragma unroll
        for (int it = 0; it < CH / 256; ++it) {
            int e = base + it * 256 + tid;
            if (e < E) atomicAdd(&scnt[dst[e] >> 8], 1);
        }
        __syncthreads();
        if (tid < nbuck) {
            int c = scnt[tid];
            sbase[tid] = c ? atomicAdd(&bcur[tid], c) : 0;
        }
        __syncthreads();
        scnt[tid] = 0;
        __syncthreads();
#pragma unroll
        for (int it = 0; it < CH / 256; ++it) {
            int e = base + it * 256 + tid;
            if (e >= E) continue;
            int d = dst[e];
            int b = d >> 8;
            int p = sbase[b] + atomicAdd(&scnt[b], 1);
            ebuf[p] = ((u32)(d & 255) << 24) | ((u32)et[e] << 16) | (u32)src[e];
        }
    } else {
        bool f = (*flag != 0);
        int m = blockIdx.x - nblkE;   // 0..17: layer = m/9, plane c = m%9
        int layer = m / 9, c = m % 9;
        size_t esz = f ? 4 : 2;
        const char* sp;
        if (layer == 0) sp = (c < R_) ? ((const char*)W1r + (size_t)c * D * D * esz) : (const char*)lW1r;
        else            sp = (c < R_) ? ((const char*)W2r + (size_t)c * D * D * esz) : (const char*)lW2r;
        int tid = threadIdx.x;
        u16* dstp = wt + (size_t)m * 16384;
        for (int i = tid; i < 16384; i += 256) {
            int wvv = i >> 11;
            int ks  = (i >> 9) & 3;
            int ln  = (i >> 3) & 63;
            int j   = i & 7;
            int k   = ks * 32 + (ln >> 4) * 8 + j;
            int col = wvv * 16 + (ln & 15);
            int idx = k * 128 + col;
            dstp[i] = f ? f2bf(((const float*)sp)[idx]) : ((const u16*)sp)[idx];
        }
    }
}

// one block per bucket: 2048-bin (dstlo*8 + et) counting sort -> offs + rowidx
// rowidx rec = (dst&31)<<19 | (et<<16) | src  -> rec>>16 is a (row,rel) flush key
__global__ __launch_bounds__(256)
void csr_emit(const u32* __restrict__ ebuf, const int* __restrict__ bstart,
              int* __restrict__ offs, int* __restrict__ rowidx, int N) {
    __shared__ int hist[2048], excl[2048], cur[2048];
    __shared__ int wpart[4];
    int b = blockIdx.x, tid = threadIdx.x;
    int lo = bstart[b], hi = bstart[b + 1];
    for (int i = tid; i < 2048; i += 256) { hist[i] = 0; cur[i] = 0; }
    __syncthreads();
    for (int i = lo + tid; i < hi; i += 256) {
        u32 rec = ebuf[i];
        int key = (int)((rec >> 24) << 3) | (int)((rec >> 16) & 7u);
        atomicAdd(&hist[key], 1);
    }
    __syncthreads();
    int loc[8]; int tsum = 0;
#pragma unroll
    for (int k = 0; k < 8; ++k) { loc[k] = tsum; tsum += hist[tid * 8 + k]; }
    int lane = tid & 63, wid = tid >> 6;
    int s = tsum;
#pragma unroll
    for (int off = 1; off < 64; off <<= 1) {
        int t = __shfl_up(s, off, 64);
        if (lane >= off) s += t;
    }
    if (lane == 63) wpart[wid] = s;
    __syncthreads();
    int add = 0;
    for (int w = 0; w < wid; ++w) add += wpart[w];
    int tex = add + s - tsum;
#pragma unroll
    for (int k = 0; k < 8; ++k) excl[tid * 8 + k] = tex + loc[k];
    int node = (b << 8) + tid;
    if (node < N) offs[node] = lo + tex;
    __syncthreads();
    for (int i = lo + tid; i < hi; i += 256) {
        u32 rec = ebuf[i];
        int key = (int)((rec >> 24) << 3) | (int)((rec >> 16) & 7u);
        int p = lo + excl[key] + atomicAdd(&cur[key], 1);
        rowidx[p] = (int)(((rec >> 24) & 31u) << 19) | (int)(rec & 0x7FFFFu);
    }
}

// first (row,rel)-key boundary at index >= s within [j0, j1); wave-uniform result
__device__ __forceinline__ int find_boundary(const int* __restrict__ rowidx,
                                             int s, int j0, int j1, int lane)
{
    if (s <= j0) return j0;
    if (s >= j1) return j1;
    int prev = rowidx[s - 1] >> 16;    // uniform scalar load
    for (;;) {
        int w = j1 - s; if (w > 64) w = 64;
        int rec = rowidx[s + (lane < w ? lane : w - 1)];
        unsigned long long m = __ballot((rec >> 16) != prev);
        if (w < 64) m &= (1ull << w) - 1ull;
        if (m) return s + (int)__ffsll((long long)m) - 1;
        s += w;
        if (s >= j1) return j1;
    }
}

// ==== fused layer: BM=16 rows per block, 8 waves, balanced edge slicing ====
// X is f32 [M][128]. Phase 1 (gather): the block's edge range is split evenly
//   across the 8 waves at (row,rel)-key boundaries (run-grabbing; exclusive key
//   ownership -> race-free flushes). Per edge: readlane (uniform src/key) +
//   f32x2 load (8 B/lane, full row across 64 lanes) + one v_pk_add_f32.
//   Flush rounds the f32 sum once to bf16 into plane [rel][row][128] (XOR swz).
//   Self plane: per-wave f32 loads + pack (rows 2wv, 2wv+1).
// Phase 2: C[16x128] = sum_c planes[c] @ W_c (K=(R+1)*128); wave wv owns 16 cols.
// mode 0: +bias, relu, f32 h out. mode 1: +bias, row-L2-normalize, f32/bf16 out.
__global__ __launch_bounds__(512, 8)
void rel_layer_fused(const float* __restrict__ xc, const float* __restrict__ xo,
                     const int* __restrict__ offs, const int* __restrict__ rowidx,
                     const u16* __restrict__ wt,
                     const void* __restrict__ bias_raw,
                     const int* __restrict__ flag,
                     int M, int R_, int mode, void* __restrict__ out)
{
    __shared__ u16 As[9 * BM * D];   // 36864 B -> 4 blocks/CU (32 waves/CU)
    const bool f = (*flag != 0);
    const float* Xf = f ? xo : xc;

    const int row0 = blockIdx.x * BM;
    const int tid  = threadIdx.x;
    const int lane = tid & 63;
    const int wv   = tid >> 6;        // 0..7
    const int quad = lane >> 4;
    const int l16  = lane & 15;
    u32* plane = (u32*)As;

    // ---- block edge range + this wave's balanced slice (loads issued early) ----
    int i0 = row0 < M ? row0 : M;
    int i1 = row0 + BM < M ? row0 + BM : M;
    int j0 = offs[i0], j1 = offs[i1];
    long long jlen = j1 - j0;
    int s0 = j0 + (int)((jlen * wv) >> 3);
    int s1 = j0 + (int)((jlen * (wv + 1)) >> 3);
    int bs = find_boundary(rowidx, s0, j0, j1, lane);
    int be = find_boundary(rowidx, s1, j0, j1, lane);

    // ---- self plane (plane 8): rows 2wv, 2wv+1, f32 load -> bf16 pack ----
#pragma unroll
    for (int rr = 0; rr < 2; ++rr) {
        int rl = wv * 2 + rr;
        int rg = row0 + rl; if (rg >= M) rg = M - 1;
        f32x2 v = *(const f32x2*)(Xf + (size_t)rg * D + lane * 2);
        plane[(8 * BM + rl) * 64 + (lane ^ (rl << 2))] = pack_bf2(v[0], v[1]);
    }

    // ---- zero relation planes 0..7 cooperatively (8192 u32 = 4096 u32x2) ----
    {
        u32x2* pz = (u32x2*)As;
        u32x2 z; z[0] = 0; z[1] = 0;
#pragma unroll
        for (int i = 0; i < 8; ++i) pz[i * 512 + tid] = z;
    }
    __syncthreads();   // zeros visible before any flush

    // ---- gather phase: linear scan of [bs, be), rolling f32 accumulator ----
    {
        const float* XL = Xf + lane * 2;   // per-lane feature base
        int key = -1;
        f32x2 acc2; acc2[0] = 0.f; acc2[1] = 0.f;
        int base = bs;
        while (base < be) {
            int wlen = be - base; if (wlen > 64) wlen = 64;
            int vrec = rowidx[base + (lane < wlen ? lane : wlen - 1)];
            for (int pos = 0; pos < wlen; pos += 16) {
                int nb = wlen - pos; if (nb > 16) nb = 16;
                int sr[16]; f32x2 g[16];
#pragma unroll
                for (int k = 0; k < 16; ++k) {
                    if (k < nb) {
                        sr[k] = __builtin_amdgcn_readlane(vrec, pos + k);
                        g[k] = *(const f32x2*)(XL + ((u32)(sr[k] & 0xffff) << 7));
                    }
                }
#pragma unroll
                for (int k = 0; k < 16; ++k) {
                    if (k < nb) {
                        int nk = sr[k] >> 16;
                        if (nk != key) {          // (row,rel) boundary: flush
                            if (key >= 0) {
                                int rl_ = ((key >> 3) - row0) & 31;
                                plane[(((key & 7) * BM + rl_) << 6) + (lane ^ (rl_ << 2))]
                                    = pack_bf2(acc2[0], acc2[1]);
                            }
                            key = nk; acc2[0] = 0.f; acc2[1] = 0.f;
                        }
                        acc2 += g[k];
                    }
                }
            }
            base += wlen;
        }
        if (key >= 0) {
            int rl_ = ((key >> 3) - row0) & 31;
            plane[(((key & 7) * BM + rl_) << 6) + (lane ^ (rl_ << 2))]
                = pack_bf2(acc2[0], acc2[1]);
        }
    }

    __syncthreads();   // planes complete

    // ---- MFMA phase: wave wv computes rows 0..15 x cols [wv*16, wv*16+16) ----
    f32x4 acc = (f32x4)0.f;
    for (int c = 0; c <= R_; ++c) {
        int cidx = (c < R_) ? c : 8;
        const u16* Bt = wt + (size_t)cidx * 16384 + (size_t)wv * 2048 + lane * 8;
        s16x8 bfr[4];
#pragma unroll
        for (int ks = 0; ks < 4; ++ks)
            bfr[ks] = *(const s16x8*)(Bt + ks * 512);
#pragma unroll
        for (int ks = 0; ks < 4; ++ks) {
            int chp = (ks * 4 + quad) ^ l16;
            s16x8 a = *(const s16x8*)(As + (cidx * BM + l16) * D + chp * 8);
            acc = __builtin_amdgcn_mfma_f32_16x16x32_bf16(a, bfr[ks], acc, 0, 0, 0);
        }
    }

    const int col = wv * 16 + l16;     // 0..127
    const float b = f ? ((const float*)bias_raw)[col]
                      : bf2f(((const u16*)bias_raw)[col]);

    if (mode == 0) {
        // h is f32: write f32x2 per even-l16 lane pair
        f32x2* o = (f32x2*)out;
#pragma unroll
        for (int i = 0; i < 4; ++i) {
            int r = row0 + quad * 4 + i;
            float v = fmaxf(acc[i] + b, 0.f);
            float vp = __shfl_xor(v, 1, 64);
            if (!(l16 & 1) && r < M) {
                f32x2 w; w[0] = v; w[1] = vp;
                o[(size_t)r * 64 + (col >> 1)] = w;
            }
        }
    } else {
        float v[4];
        float pr[4];
#pragma unroll
        for (int i = 0; i < 4; ++i) {
            v[i] = acc[i] + b;
            float p = v[i] * v[i];
            p += __shfl_xor(p, 1, 64);
            p += __shfl_xor(p, 2, 64);
            p += __shfl_xor(p, 4, 64);
            p += __shfl_xor(p, 8, 64);
            pr[i] = p;                 // this wave's 16-col partial for row quad*4+i
        }
        __syncthreads();               // planes no longer needed: reuse as scratch
        float* fs = (float*)As;        // fs[row*8 + wv], scales at fs[128..143]
        if (l16 == 0) {
#pragma unroll
            for (int i = 0; i < 4; ++i) fs[(quad * 4 + i) * 8 + wv] = pr[i];
        }
        __syncthreads();
        if (tid < 16) {
            float s = 0.f;
#pragma unroll
            for (int w = 0; w < 8; ++w) s += fs[tid * 8 + w];
            fs[128 + tid] = 1.f / fmaxf(sqrtf(s), 1e-12f);
        }
        __syncthreads();
#pragma unroll
        for (int i = 0; i < 4; ++i) {
            int rl = quad * 4 + i;
            int r = row0 + rl;
            float sc = fs[128 + rl];
            float a0 = v[i] * sc;
            float ap = __shfl_xor(a0, 1, 64);
            if (!(l16 & 1) && r < M) {
                if (f) {
                    f32x2 w; w[0] = a0; w[1] = ap;
                    ((f32x2*)out)[(size_t)r * 64 + (col >> 1)] = w;
                } else {
                    ((u32*)out)[(size_t)r * 64 + (col >> 1)] = pack_bf2(a0, ap);
                }
            }
        }
    }
}

static inline size_t align256(size_t x) { return (x + 255) & ~(size_t)255; }

extern "C" void kernel_launch(void* const* d_in, const int* in_sizes, int n_in,
                              void* d_out, int out_size, void* d_ws, size_t ws_size,
                              hipStream_t stream)
{
    const void* x_in   = d_in[0];
    const void* W1_in  = d_in[1];
    const void* lW1_in = d_in[2];
    const void* b1_in  = d_in[3];
    const void* W2_in  = d_in[4];
    const void* lW2_in = d_in[5];
    const void* b2_in  = d_in[6];
    const int* src = (const int*)d_in[7];
    const int* dst = (const int*)d_in[8];
    const int* et  = (const int*)d_in[9];

    const int N = in_sizes[0] / D;            // 50000
    const int E = in_sizes[7];                // 800000
    const int R = in_sizes[1] / (D * D);      // 8
    const int nbuck = (N + 255) >> 8;         // 196

    const long long ND = (long long)N * D;

    size_t off = 0;
    auto alloc = [&](size_t bytes) { size_t o = off; off = align256(off + bytes); return o; };
    size_t o_flag = alloc(256);
    size_t o_xc   = alloc((size_t)ND * 4);    // f32 expansion of x (bf16-input case)
    size_t o_h    = alloc((size_t)ND * 4);    // f32 hidden layer
    size_t o_offs = alloc((size_t)(N + 1) * 4);
    size_t o_gcnt = alloc(1024);
    size_t o_bst  = alloc(1040 * 4);
    size_t o_bcur = alloc(1024);
    size_t o_ebuf = alloc((size_t)E * 4);
    size_t o_ridx = alloc((size_t)E * 4);
    size_t o_wt   = alloc((size_t)2 * 9 * D * D * 2);  // fragment-ordered weights
    (void)ws_size;

    char* ws = (char*)d_ws;
    int* flag   = (int*)(ws + o_flag);
    float* x_cf = (float*)(ws + o_xc);
    float* h    = (float*)(ws + o_h);
    int* offs   = (int*)(ws + o_offs);
    int* gcnt   = (int*)(ws + o_gcnt);
    int* bstart = (int*)(ws + o_bst);
    int* bcur   = (int*)(ws + o_bcur);
    u32* ebuf   = (u32*)(ws + o_ebuf);
    int* rowidx = (int*)(ws + o_ridx);
    u16* wt     = (u16*)(ws + o_wt);

    dim3 blk(256, 1, 1);
    int mb    = (N + BM - 1) / BM;            // 3125 blocks
    int nblkE = (E + CH - 1) / CH;            // 391
    long long n4 = ND / 4;
    int nconv = (int)((n4 + 255) / 256);      // 6250

    detect_dtype<<<dim3(1), blk, 0, stream>>>((const u16*)x_in, flag, gcnt, nbuck);

    // x bf16->f32 expansion (only if needed) + csr_count in one launch
    prep1<<<dim3(nconv + nblkE), blk, 0, stream>>>(
        (const u32x2*)x_in, (float4*)x_cf, n4, flag, dst, gcnt, E, nbuck, nconv);

    csr_scan<<<dim3(1), blk, 0, stream>>>(gcnt, bstart, bcur, nbuck, N, E, offs);

    // edge partition + weight-fragment build in one launch
    prep2<<<dim3(nblkE + 18), blk, 0, stream>>>(
        src, dst, et, bcur, ebuf, E, N, nbuck, nblkE,
        W1_in, lW1_in, W2_in, lW2_in, flag, R, wt);

    csr_emit<<<dim3(nbuck), blk, 0, stream>>>(ebuf, bstart, offs, rowidx, N);

    // layer 1: fused gather + deep GEMM (K=(R+1)*128), bias+relu -> f32 h
    rel_layer_fused<<<dim3(mb), dim3(512), 0, stream>>>(
        x_cf, (const float*)x_in, offs, rowidx, wt,
        b1_in, flag, N, R, 0, h);

    // layer 2: fused gather + deep GEMM, bias + row-L2-normalize
    rel_layer_fused<<<dim3(mb), dim3(512), 0, stream>>>(
        h, h, offs, rowidx, wt + (size_t)9 * D * D,
        b2_in, flag, N, R, 1, d_out);
}

// Round 9
// 274.531 us; speedup vs baseline: 1.2355x; 1.2355x over previous
//
#include <hip/hip_runtime.h>
#include <hip/hip_bf16.h>

#define D 128
#define CH 2048   // edges per block in CSR partition passes
#define BM 16     // dst rows per fused block (8 waves, balanced edge slicing)

typedef unsigned int u32;
typedef unsigned short u16;
typedef __attribute__((ext_vector_type(8))) short s16x8;
typedef __attribute__((ext_vector_type(4))) float f32x4;
typedef __attribute__((ext_vector_type(2))) float f32x2;
typedef __attribute__((ext_vector_type(2))) u32 u32x2;

__device__ __forceinline__ float bf2f(u16 u) {
    union { u32 u; float f; } v; v.u = ((u32)u) << 16; return v.f;
}
__device__ __forceinline__ u16 f2bf(float f) {
    union { float f; u32 u; } v; v.f = f;
    return (u16)((v.u + 0x7fffu + ((v.u >> 16) & 1u)) >> 16);
}
__device__ __forceinline__ u32 pack_bf2(float a, float b) {
    __hip_bfloat162 t = __float22bfloat162_rn(make_float2(a, b));
    union { __hip_bfloat162 t; u32 u; } v; v.t = t; return v.u;
}

// ---- dtype detector (also zeroes gcnt for the CSR build) ----
__global__ void detect_dtype(const u16* __restrict__ x, int* __restrict__ flag,
                             int* __restrict__ gcnt, int nbuck) {
    __shared__ int cnt;
    if (threadIdx.x == 0) cnt = 0;
    __syncthreads();
    if ((int)threadIdx.x < nbuck) gcnt[threadIdx.x] = 0;
    u16 u = x[2 * threadIdx.x];
    int e = (u >> 7) & 0xFF;
    if (e >= 96 && e <= 150) atomicAdd(&cnt, 1);
    __syncthreads();
    if (threadIdx.x == 0) *flag = (cnt >= 128) ? 0 : 1;
}

// ---- prep1: blocks [0,nconv) convert x fp32->bf16 (4 elems/thread, only if flag);
//             blocks [nconv, nconv+nblkE) run csr_count ----
__global__ __launch_bounds__(256)
void prep1(const float4* __restrict__ xin, u32x2* __restrict__ xout,
           long long n4, const int* __restrict__ flag,
           const int* __restrict__ dst, int* __restrict__ gcnt,
           int E, int nbuck, int nconv)
{
    if ((int)blockIdx.x < nconv) {
        if (*flag == 0) return;
        long long i = (long long)blockIdx.x * 256 + threadIdx.x;
        if (i >= n4) return;
        float4 v = xin[i];
        u32x2 o;
        o[0] = pack_bf2(v.x, v.y);
        o[1] = pack_bf2(v.z, v.w);
        xout[i] = o;
    } else {
        __shared__ int scnt[256];
        int tid = threadIdx.x;
        scnt[tid] = 0;
        __syncthreads();
        int base = (blockIdx.x - nconv) * CH;
#pragma unroll
        for (int it = 0; it < CH / 256; ++it) {
            int e = base + it * 256 + tid;
            if (e < E) atomicAdd(&scnt[dst[e] >> 8], 1);
        }
        __syncthreads();
        if (tid < nbuck && scnt[tid] > 0) atomicAdd(&gcnt[tid], scnt[tid]);
    }
}

__global__ __launch_bounds__(256)
void csr_scan(const int* __restrict__ gcnt, int* __restrict__ bstart, int* __restrict__ bcur,
              int nbuck, int N_, int E_, int* __restrict__ offs) {
    __shared__ int wpart[4];
    int tid = threadIdx.x, lane = tid & 63, wid = tid >> 6;
    int v = (tid < nbuck) ? gcnt[tid] : 0;
    int s = v;
#pragma unroll
    for (int off = 1; off < 64; off <<= 1) {
        int t = __shfl_up(s, off, 64);
        if (lane >= off) s += t;
    }
    if (lane == 63) wpart[wid] = s;
    __syncthreads();
    int add = 0;
    for (int w = 0; w < wid; ++w) add += wpart[w];
    int excl = add + s - v;
    if (tid <= nbuck) bstart[tid] = excl;
    if (tid < nbuck)  bcur[tid]  = excl;
    if (tid == 0) offs[N_] = E_;
}

// ---- prep2: blocks [0,nblkE) partition edges into bucket-contiguous ebuf
//             (rec = (dst&255)<<24 | (et<<16) | src);
//             blocks [nblkE, nblkE+18) build fragment-ordered weights wt ----
// wt[layer][plane 0..8][wv:8][ks:4][lane:64][j:8] bf16 ;
// element = W[k = ks*32 + (lane>>4)*8 + j][col = wv*16 + (lane&15)] ; plane 8 = loopW
__global__ __launch_bounds__(256)
void prep2(const int* __restrict__ src, const int* __restrict__ dst,
           const int* __restrict__ et, int* __restrict__ bcur,
           u32* __restrict__ ebuf, int E, int N, int nbuck, int nblkE,
           const void* __restrict__ W1r, const void* __restrict__ lW1r,
           const void* __restrict__ W2r, const void* __restrict__ lW2r,
           const int* __restrict__ flag, int R_, u16* __restrict__ wt)
{
    if ((int)blockIdx.x < nblkE) {
        __shared__ int scnt[256], sbase[256];
        int tid = threadIdx.x;
        scnt[tid] = 0;
        __syncthreads();
        int base = blockIdx.x * CH;
#pragma unroll
        for (int it = 0; it < CH / 256; ++it) {
            int e = base + it * 256 + tid;
            if (e < E) atomicAdd(&scnt[dst[e] >> 8], 1);
        }
        __syncthreads();
        if (tid < nbuck) {
            int c = scnt[tid];
            sbase[tid] = c ? atomicAdd(&bcur[tid], c) : 0;
        }
        __syncthreads();
        scnt[tid] = 0;
        __syncthreads();
#pragma unroll
        for (int it = 0; it < CH / 256; ++it) {
            int e = base + it * 256 + tid;
            if (e >= E) continue;
            int d = dst[e];
            int b = d >> 8;
            int p = sbase[b] + atomicAdd(&scnt[b], 1);
            ebuf[p] = ((u32)(d & 255) << 24) | ((u32)et[e] << 16) | (u32)src[e];
        }
    } else {
        bool f = (*flag != 0);
        int m = blockIdx.x - nblkE;   // 0..17: layer = m/9, plane c = m%9
        int layer = m / 9, c = m % 9;
        size_t esz = f ? 4 : 2;
        const char* sp;
        if (layer == 0) sp = (c < R_) ? ((const char*)W1r + (size_t)c * D * D * esz) : (const char*)lW1r;
        else            sp = (c < R_) ? ((const char*)W2r + (size_t)c * D * D * esz) : (const char*)lW2r;
        int tid = threadIdx.x;
        u16* dstp = wt + (size_t)m * 16384;
        for (int i = tid; i < 16384; i += 256) {
            int wvv = i >> 11;
            int ks  = (i >> 9) & 3;
            int ln  = (i >> 3) & 63;
            int j   = i & 7;
            int k   = ks * 32 + (ln >> 4) * 8 + j;
            int col = wvv * 16 + (ln & 15);
            int idx = k * 128 + col;
            dstp[i] = f ? f2bf(((const float*)sp)[idx]) : ((const u16*)sp)[idx];
        }
    }
}

// one block per bucket: 2048-bin (dstlo*8 + et) counting sort -> offs + rowidx
// rowidx rec = key2<<16 | src, key2 = (et<<4)|(dst&15) == LDS plane-row index.
// (dst&15 suffices: BM=16 blocks; (dst-row0)&15 == dst&15 for row0 % 16 == 0.)
__global__ __launch_bounds__(256)
void csr_emit(const u32* __restrict__ ebuf, const int* __restrict__ bstart,
              int* __restrict__ offs, int* __restrict__ rowidx, int N, int E_) {
    __shared__ int hist[2048], excl[2048], cur[2048];
    __shared__ int wpart[4];
    int b = blockIdx.x, tid = threadIdx.x;
    int lo = bstart[b], hi = bstart[b + 1];
    if (b == 0 && tid < 64) rowidx[E_ + tid] = 0;   // pad: safe 16-wide overread
    for (int i = tid; i < 2048; i += 256) { hist[i] = 0; cur[i] = 0; }
    __syncthreads();
    for (int i = lo + tid; i < hi; i += 256) {
        u32 rec = ebuf[i];
        int key = (int)((rec >> 24) << 3) | (int)((rec >> 16) & 7u);
        atomicAdd(&hist[key], 1);
    }
    __syncthreads();
    int loc[8]; int tsum = 0;
#pragma unroll
    for (int k = 0; k < 8; ++k) { loc[k] = tsum; tsum += hist[tid * 8 + k]; }
    int lane = tid & 63, wid = tid >> 6;
    int s = tsum;
#pragma unroll
    for (int off = 1; off < 64; off <<= 1) {
        int t = __shfl_up(s, off, 64);
        if (lane >= off) s += t;
    }
    if (lane == 63) wpart[wid] = s;
    __syncthreads();
    int add = 0;
    for (int w = 0; w < wid; ++w) add += wpart[w];
    int tex = add + s - tsum;
#pragma unroll
    for (int k = 0; k < 8; ++k) excl[tid * 8 + k] = tex + loc[k];
    int node = (b << 8) + tid;
    if (node < N) offs[node] = lo + tex;
    __syncthreads();
    for (int i = lo + tid; i < hi; i += 256) {
        u32 rec = ebuf[i];
        int key = (int)((rec >> 24) << 3) | (int)((rec >> 16) & 7u);
        int p = lo + excl[key] + atomicAdd(&cur[key], 1);
        u32 key2 = (((rec >> 16) & 7u) << 4) | ((rec >> 24) & 15u);
        rowidx[p] = (int)(key2 << 16) | (int)(rec & 0xFFFFu);
    }
}

// first key boundary at index >= s within [j0, j1); wave-uniform result
__device__ __forceinline__ int find_boundary(const int* __restrict__ rowidx,
                                             int s, int j0, int j1, int lane)
{
    if (s <= j0) return j0;
    if (s >= j1) return j1;
    int prev = rowidx[s - 1] >> 16;    // uniform scalar load
    for (;;) {
        int w = j1 - s; if (w > 64) w = 64;
        int rec = rowidx[s + (lane < w ? lane : w - 1)];
        unsigned long long m = __ballot((rec >> 16) != prev);
        if (w < 64) m &= (1ull << w) - 1ull;
        if (m) return s + (int)__ffsll((long long)m) - 1;
        s += w;
        if (s >= j1) return j1;
    }
}

// ==== fused layer: BM=16 rows per block, 8 waves, balanced edge slicing ====
// Phase 1 (gather): block's edge range split evenly across waves at key
//   boundaries (exclusive key ownership -> race-free flushes). Edge records are
//   loaded via wave-uniform addresses (compiler -> s_load, SGPR results): no
//   readlanes; per-edge VALU = unpack(2) + v_pk_add_f32(1). key2 payload IS the
//   LDS plane-row, so flush addressing is 2 VALU. Self plane via global_load_lds.
// Phase 2: C[16x128] = sum_c planes[c] @ W_c (K=(R+1)*128); wave wv owns 16 cols.
// mode 0: +bias, relu, bf16 h. mode 1: +bias, row-L2-normalize, f32/bf16 out.
__global__ __launch_bounds__(512, 8)
void rel_layer_fused(const u16* __restrict__ xc, const u16* __restrict__ xo,
                     const int* __restrict__ offs, const int* __restrict__ rowidx,
                     const u16* __restrict__ wt,
                     const void* __restrict__ bias_raw,
                     const int* __restrict__ flag,
                     int M, int R_, int mode, void* __restrict__ out)
{
    __shared__ u16 As[9 * BM * D];   // 36864 B -> 4 blocks/CU (32 waves/CU)
    const bool f = (*flag != 0);
    const u16* X = f ? xc : xo;

    const int row0 = blockIdx.x * BM;
    const int tid  = threadIdx.x;
    const int lane = tid & 63;
    const int wv   = tid >> 6;        // 0..7
    const int quad = lane >> 4;
    const int l16  = lane & 15;
    u32* plane = (u32*)As;

    // ---- stage self plane (plane 8): waves 0..3, 4 rows each ----
    if (wv < 4) {
        auto* lds0 = (__attribute__((address_space(3))) char*)As;
        int rl = wv * 4 + quad;
        int rg = row0 + rl; if (rg >= M) rg = M - 1;
        int cg = l16 ^ rl;            // pre-swizzled source chunk
        const u16* gp = X + (size_t)rg * D + cg * 8;
        __builtin_amdgcn_global_load_lds(
            (const __attribute__((address_space(1))) void*)gp,
            (__attribute__((address_space(3))) void*)(lds0 + 8 * BM * 256 + wv * 1024),
            16, 0, 0);
    }

    // ---- block edge range + this wave's balanced slice ----
    int i0 = row0 < M ? row0 : M;
    int i1 = row0 + BM < M ? row0 + BM : M;
    int j0 = offs[i0], j1 = offs[i1];
    long long jlen = j1 - j0;
    int s0 = j0 + (int)((jlen * wv) >> 3);
    int s1 = j0 + (int)((jlen * (wv + 1)) >> 3);
    int bs = find_boundary(rowidx, s0, j0, j1, lane);
    int be = find_boundary(rowidx, s1, j0, j1, lane);

    // ---- zero relation planes 0..7 cooperatively (8192 u32 = 4096 u32x2) ----
    {
        u32x2* pz = (u32x2*)As;
        u32x2 z; z[0] = 0; z[1] = 0;
#pragma unroll
        for (int i = 0; i < 8; ++i) pz[i * 512 + tid] = z;
    }
    __syncthreads();   // zeros visible + self plane staged before any flush

    // ---- gather phase: scalar-record linear scan of [bs, be) ----
    if (bs < be) {
        const u32* X32 = (const u32*)X;   // row stride 64 u32
        int key = rowidx[bs] >> 16;       // prime (uniform scalar load)
        f32x2 acc2; acc2[0] = 0.f; acc2[1] = 0.f;
        int p = bs;

#define PROC1(RK, GK) do {                                                    \
        int nk_ = (RK) >> 16;                                                 \
        if (nk_ != key) {                                                     \
            plane[(key << 6) + (lane ^ ((key & 15) << 2))]                    \
                = pack_bf2(acc2[0], acc2[1]);                                 \
            key = nk_; acc2[0] = 0.f; acc2[1] = 0.f;                          \
        }                                                                     \
        union { u32 u; float f; } lo_, hi_;                                   \
        lo_.u = (GK) << 16; hi_.u = (GK) & 0xffff0000u;                       \
        f32x2 e_; e_[0] = lo_.f; e_[1] = hi_.f;                               \
        acc2 += e_; } while (0)

        while (p + 16 <= be) {
            int r[16]; u32 g[16];
#pragma unroll
            for (int k = 0; k < 16; ++k) r[k] = rowidx[p + k];   // s_load (uniform)
#pragma unroll
            for (int k = 0; k < 16; ++k)
                g[k] = *(X32 + (((u32)r[k] & 0xffffu) << 6) + lane);
#pragma unroll
            for (int k = 0; k < 16; ++k) PROC1(r[k], g[k]);
            p += 16;
        }
        if (p < be) {
            int nb = be - p;
            int r[16]; u32 g[16];
#pragma unroll
            for (int k = 0; k < 16; ++k) r[k] = rowidx[p + k];   // overreads pad
#pragma unroll
            for (int k = 0; k < 16; ++k)
                g[k] = *(X32 + (((u32)r[k] & 0xffffu) << 6) + lane);
#pragma unroll
            for (int k = 0; k < 16; ++k)
                if (k < nb) PROC1(r[k], g[k]);
        }
        plane[(key << 6) + (lane ^ ((key & 15) << 2))] = pack_bf2(acc2[0], acc2[1]);
#undef PROC1
    }

    __syncthreads();   // planes complete

    // ---- MFMA phase: wave wv computes rows 0..15 x cols [wv*16, wv*16+16) ----
    f32x4 acc = (f32x4)0.f;
    for (int c = 0; c <= R_; ++c) {
        int cidx = (c < R_) ? c : 8;
        const u16* Bt = wt + (size_t)cidx * 16384 + (size_t)wv * 2048 + lane * 8;
        s16x8 bfr[4];
#pragma unroll
        for (int ks = 0; ks < 4; ++ks)
            bfr[ks] = *(const s16x8*)(Bt + ks * 512);
#pragma unroll
        for (int ks = 0; ks < 4; ++ks) {
            int chp = (ks * 4 + quad) ^ l16;
            s16x8 a = *(const s16x8*)(As + (cidx * BM + l16) * D + chp * 8);
            acc = __builtin_amdgcn_mfma_f32_16x16x32_bf16(a, bfr[ks], acc, 0, 0, 0);
        }
    }

    const int col = wv * 16 + l16;     // 0..127
    const float b = f ? ((const float*)bias_raw)[col]
                      : bf2f(((const u16*)bias_raw)[col]);

    if (mode == 0) {
        u32* o = (u32*)out;
#pragma unroll
        for (int i = 0; i < 4; ++i) {
            int r = row0 + quad * 4 + i;
            float v = fmaxf(acc[i] + b, 0.f);
            float vp = __shfl_xor(v, 1, 64);
            if (!(l16 & 1) && r < M)
                o[(size_t)r * 64 + (col >> 1)] = pack_bf2(v, vp);
        }
    } else {
        float v[4];
        float pr[4];
#pragma unroll
        for (int i = 0; i < 4; ++i) {
            v[i] = acc[i] + b;
            float p = v[i] * v[i];
            p += __shfl_xor(p, 1, 64);
            p += __shfl_xor(p, 2, 64);
            p += __shfl_xor(p, 4, 64);
            p += __shfl_xor(p, 8, 64);
            pr[i] = p;                 // this wave's 16-col partial for row quad*4+i
        }
        __syncthreads();               // planes no longer needed: reuse as scratch
        float* fs = (float*)As;        // fs[row*8 + wv], scales at fs[128..143]
        if (l16 == 0) {
#pragma unroll
            for (int i = 0; i < 4; ++i) fs[(quad * 4 + i) * 8 + wv] = pr[i];
        }
        __syncthreads();
        if (tid < 16) {
            float s = 0.f;
#pragma unroll
            for (int w = 0; w < 8; ++w) s += fs[tid * 8 + w];
            fs[128 + tid] = 1.f / fmaxf(sqrtf(s), 1e-12f);
        }
        __syncthreads();
#pragma unroll
        for (int i = 0; i < 4; ++i) {
            int rl = quad * 4 + i;
            int r = row0 + rl;
            float sc = fs[128 + rl];
            float a0 = v[i] * sc;
            float ap = __shfl_xor(a0, 1, 64);
            if (!(l16 & 1) && r < M) {
                if (f) {
                    f32x2 w; w[0] = a0; w[1] = ap;
                    ((f32x2*)out)[(size_t)r * 64 + (col >> 1)] = w;
                } else {
                    ((u32*)out)[(size_t)r * 64 + (col >> 1)] = pack_bf2(a0, ap);
                }
            }
        }
    }
}

static inline size_t align256(size_t x) { return (x + 255) & ~(size_t)255; }

extern "C" void kernel_launch(void* const* d_in, const int* in_sizes, int n_in,
                              void* d_out, int out_size, void* d_ws, size_t ws_size,
                              hipStream_t stream)
{
    const void* x_in   = d_in[0];
    const void* W1_in  = d_in[1];
    const void* lW1_in = d_in[2];
    const void* b1_in  = d_in[3];
    const void* W2_in  = d_in[4];
    const void* lW2_in = d_in[5];
    const void* b2_in  = d_in[6];
    const int* src = (const int*)d_in[7];
    const int* dst = (const int*)d_in[8];
    const int* et  = (const int*)d_in[9];

    const int N = in_sizes[0] / D;            // 50000
    const int E = in_sizes[7];                // 800000
    const int R = in_sizes[1] / (D * D);      // 8
    const int nbuck = (N + 255) >> 8;         // 196

    const long long ND = (long long)N * D;

    size_t off = 0;
    auto alloc = [&](size_t bytes) { size_t o = off; off = align256(off + bytes); return o; };
    size_t o_flag = alloc(256);
    size_t o_xc   = alloc((size_t)ND * 2);
    size_t o_h    = alloc((size_t)ND * 2);
    size_t o_offs = alloc((size_t)(N + 1) * 4);
    size_t o_gcnt = alloc(1024);
    size_t o_bst  = alloc(1040 * 4);
    size_t o_bcur = alloc(1024);
    size_t o_ebuf = alloc((size_t)E * 4);
    size_t o_ridx = alloc((size_t)(E + 64) * 4);       // +64 pad for overread
    size_t o_wt   = alloc((size_t)2 * 9 * D * D * 2);  // fragment-ordered weights
    (void)ws_size;

    char* ws = (char*)d_ws;
    int* flag   = (int*)(ws + o_flag);
    u16* x_c    = (u16*)(ws + o_xc);
    u16* h      = (u16*)(ws + o_h);
    int* offs   = (int*)(ws + o_offs);
    int* gcnt   = (int*)(ws + o_gcnt);
    int* bstart = (int*)(ws + o_bst);
    int* bcur   = (int*)(ws + o_bcur);
    u32* ebuf   = (u32*)(ws + o_ebuf);
    int* rowidx = (int*)(ws + o_ridx);
    u16* wt     = (u16*)(ws + o_wt);

    dim3 blk(256, 1, 1);
    int mb    = (N + BM - 1) / BM;            // 3125 blocks
    int nblkE = (E + CH - 1) / CH;            // 391
    long long n4 = ND / 4;
    int nconv = (int)((n4 + 255) / 256);      // 6250

    detect_dtype<<<dim3(1), blk, 0, stream>>>((const u16*)x_in, flag, gcnt, nbuck);

    // x conversion + csr_count in one launch
    prep1<<<dim3(nconv + nblkE), blk, 0, stream>>>(
        (const float4*)x_in, (u32x2*)x_c, n4, flag, dst, gcnt, E, nbuck, nconv);

    csr_scan<<<dim3(1), blk, 0, stream>>>(gcnt, bstart, bcur, nbuck, N, E, offs);

    // edge partition + weight-fragment build in one launch
    prep2<<<dim3(nblkE + 18), blk, 0, stream>>>(
        src, dst, et, bcur, ebuf, E, N, nbuck, nblkE,
        W1_in, lW1_in, W2_in, lW2_in, flag, R, wt);

    csr_emit<<<dim3(nbuck), blk, 0, stream>>>(ebuf, bstart, offs, rowidx, N, E);

    // layer 1: fused gather + deep GEMM (K=(R+1)*128), bias+relu
    rel_layer_fused<<<dim3(mb), dim3(512), 0, stream>>>(
        x_c, (const u16*)x_in, offs, rowidx, wt,
        b1_in, flag, N, R, 0, h);

    // layer 2: fused gather + deep GEMM, bias + row-L2-normalize
    rel_layer_fused<<<dim3(mb), dim3(512), 0, stream>>>(
        h, h, offs, rowidx, wt + (size_t)9 * D * D,
        b2_in, flag, N, R, 1, d_out);
}